// Round 1
// baseline (11478.967 us; speedup 1.0000x reference)
//
#include <hip/hip_runtime.h>
#include <hip/hip_bf16.h>
#include <cstddef>

// Problem constants (from reference)
#define NN 100000
#define NE 1600000
#define NH 5
#define NC 12
#define HC 60     // NH*NC
#define FN 128
#define FE 32
#define HID 16
#define NCLS 2

// ---------------------------------------------------------------------------
// qkvs: computes q,k,v,skip = X @ W? + b?  for 4 weight matrices [DIN,60].
// One block = 8 nodes, 256 threads; threads 0..239 each own (matrix, col).
// X rows staged in LDS; W columns streamed from global (L2-resident).
// ---------------------------------------------------------------------------
template<int DIN>
__global__ __launch_bounds__(256) void qkvs_kernel(
    const float* __restrict__ X,
    const float* __restrict__ Wq, const float* __restrict__ bq,
    const float* __restrict__ Wk, const float* __restrict__ bk,
    const float* __restrict__ Wv, const float* __restrict__ bv,
    const float* __restrict__ Ws, const float* __restrict__ bs,
    float* __restrict__ q, float* __restrict__ k,
    float* __restrict__ v, float* __restrict__ s)
{
    constexpr int NB = 8;
    __shared__ float xs[NB][DIN];
    const int n0 = blockIdx.x * NB;
    for (int i = threadIdx.x; i < NB * DIN; i += 256) {
        const int m = i / DIN, r = i - m * DIN;
        const int node = n0 + m;
        xs[m][r] = (node < NN) ? X[(size_t)node * DIN + r] : 0.f;
    }
    __syncthreads();

    const int j = threadIdx.x;
    if (j >= 240) return;
    const int mat = j / 60, col = j - mat * 60;
    const float* W; const float* b; float* out;
    switch (mat) {
        case 0:  W = Wq; b = bq; out = q; break;
        case 1:  W = Wk; b = bk; out = k; break;
        case 2:  W = Wv; b = bv; out = v; break;
        default: W = Ws; b = bs; out = s; break;
    }
    float acc[NB];
    #pragma unroll
    for (int m = 0; m < NB; ++m) acc[m] = 0.f;
    #pragma unroll 4
    for (int r = 0; r < DIN; ++r) {
        const float w = W[r * 60 + col];
        #pragma unroll
        for (int m = 0; m < NB; ++m) acc[m] = fmaf(xs[m][r], w, acc[m]);
    }
    const float bb = b[col];
    #pragma unroll
    for (int m = 0; m < NB; ++m) {
        const int node = n0 + m;
        if (node < NN) out[(size_t)node * 60 + col] = acc[m] + bb;
    }
}

// ---------------------------------------------------------------------------
// Fused edge pass: per edge e with (src,dst):
//   evec = edge_attr[e] @ We                        (in-register, [60])
//   alpha_h = <q[dst,h,:], k[src,h,:]+evec[h,:]>/sqrt(12)
//   w_h = exp(alpha_h - 20)    (constant shift; cancels in normalization)
//   denom[dst,h]  += w_h                            (atomic)
//   hacc[dst,hc]  += w_h * (v[src,hc] + evec[hc])   (atomic)
// No segment-max pass needed.
// ---------------------------------------------------------------------------
__global__ __launch_bounds__(256) void edge_kernel(
    const int*   __restrict__ ei,
    const float* __restrict__ ea,
    const float* __restrict__ We,
    const float* __restrict__ q, const float* __restrict__ k,
    const float* __restrict__ v,
    float* __restrict__ denom, float* __restrict__ hacc)
{
    const int e = blockIdx.x * 256 + threadIdx.x;
    if (e >= NE) return;
    const int sn = ei[e];
    const int dn = ei[NE + e];

    const float* __restrict__ earow = ea + (size_t)e * FE;

    float eacc[60];
    #pragma unroll
    for (int i = 0; i < 60; ++i) eacc[i] = 0.f;
    #pragma unroll 4
    for (int r = 0; r < FE; ++r) {
        const float a = earow[r];               // per-lane, L1-friendly
        const float* __restrict__ wrow = We + r * 60;  // wave-uniform -> s_load
        #pragma unroll
        for (int hc = 0; hc < 60; ++hc) eacc[hc] = fmaf(a, wrow[hc], eacc[hc]);
    }

    const float* __restrict__ qrow = q + (size_t)dn * 60;
    const float* __restrict__ krow = k + (size_t)sn * 60;
    const float* __restrict__ vrow = v + (size_t)sn * 60;

    float w[NH];
    #pragma unroll
    for (int h = 0; h < NH; ++h) {
        float a = 0.f;
        #pragma unroll
        for (int c = 0; c < NC; ++c) {
            const int hc = h * NC + c;
            a = fmaf(qrow[hc], krow[hc] + eacc[hc], a);
        }
        // 1/sqrt(12), minus constant shift 20 for exp-range safety
        w[h] = __expf(fmaf(a, 0.28867513459481287f, -20.0f));
        atomicAdd(&denom[(size_t)dn * NH + h], w[h]);
    }

    float* __restrict__ hrow = hacc + (size_t)dn * 60;
    #pragma unroll
    for (int h = 0; h < NH; ++h) {
        #pragma unroll
        for (int c = 0; c < NC; ++c) {
            const int hc = h * NC + c;
            atomicAdd(&hrow[hc], w[h] * (vrow[hc] + eacc[hc]));
        }
    }
}

// ---------------------------------------------------------------------------
// Epilogue: h = relu(hacc / (denom + 1e-16) + skip)
// ---------------------------------------------------------------------------
__global__ __launch_bounds__(256) void epilogue_kernel(
    const float* __restrict__ hacc, const float* __restrict__ denom,
    const float* __restrict__ sk, float* __restrict__ hout)
{
    const int idx = blockIdx.x * 256 + threadIdx.x;
    if (idx >= NN * 60) return;
    const int n = idx / 60;
    const int hc = idx - n * 60;
    const int h = hc / NC;
    const float val = hacc[idx] / (denom[(size_t)n * NH + h] + 1e-16f) + sk[idx];
    hout[idx] = fmaxf(val, 0.f);
}

// ---------------------------------------------------------------------------
// MLP head: out = relu(h @ W1 + b1) @ W2 + b2     (one thread per node)
// ---------------------------------------------------------------------------
__global__ __launch_bounds__(256) void mlp_kernel(
    const float* __restrict__ h,
    const float* __restrict__ W1, const float* __restrict__ b1,
    const float* __restrict__ W2, const float* __restrict__ b2,
    float* __restrict__ out)
{
    __shared__ float sW1[60 * HID];
    __shared__ float sb1[HID];
    __shared__ float sW2[HID * NCLS];
    __shared__ float sb2[NCLS];
    for (int i = threadIdx.x; i < 60 * HID; i += 256) sW1[i] = W1[i];
    if (threadIdx.x < HID)        sb1[threadIdx.x] = b1[threadIdx.x];
    if (threadIdx.x < HID * NCLS) sW2[threadIdx.x] = W2[threadIdx.x];
    if (threadIdx.x < NCLS)       sb2[threadIdx.x] = b2[threadIdx.x];
    __syncthreads();

    const int n = blockIdx.x * 256 + threadIdx.x;
    if (n >= NN) return;
    const float* __restrict__ hr = h + (size_t)n * 60;
    float hv[60];
    #pragma unroll
    for (int i = 0; i < 15; ++i) {
        const float4 t = ((const float4*)hr)[i];
        hv[4 * i + 0] = t.x; hv[4 * i + 1] = t.y;
        hv[4 * i + 2] = t.z; hv[4 * i + 3] = t.w;
    }
    float o0 = sb2[0], o1 = sb2[1];
    for (int j = 0; j < HID; ++j) {
        float t = sb1[j];
        #pragma unroll
        for (int i = 0; i < 60; ++i) t = fmaf(hv[i], sW1[i * HID + j], t);
        t = fmaxf(t, 0.f);
        o0 = fmaf(t, sW2[2 * j + 0], o0);
        o1 = fmaf(t, sW2[2 * j + 1], o1);
    }
    out[(size_t)n * 2 + 0] = o0;
    out[(size_t)n * 2 + 1] = o1;
}

// ---------------------------------------------------------------------------
extern "C" void kernel_launch(void* const* d_in, const int* in_sizes, int n_in,
                              void* d_out, int out_size, void* d_ws, size_t ws_size,
                              hipStream_t stream)
{
    const float* x   = (const float*)d_in[0];
    const int*   ei  = (const int*)  d_in[1];
    const float* ea  = (const float*)d_in[2];
    const float* Wq1 = (const float*)d_in[3];  const float* bq1 = (const float*)d_in[4];
    const float* Wk1 = (const float*)d_in[5];  const float* bk1 = (const float*)d_in[6];
    const float* Wv1 = (const float*)d_in[7];  const float* bv1 = (const float*)d_in[8];
    const float* We1 = (const float*)d_in[9];
    const float* Ws1 = (const float*)d_in[10]; const float* bs1 = (const float*)d_in[11];
    const float* Wq2 = (const float*)d_in[12]; const float* bq2 = (const float*)d_in[13];
    const float* Wk2 = (const float*)d_in[14]; const float* bk2 = (const float*)d_in[15];
    const float* Wv2 = (const float*)d_in[16]; const float* bv2 = (const float*)d_in[17];
    const float* We2 = (const float*)d_in[18];
    const float* Ws2 = (const float*)d_in[19]; const float* bs2 = (const float*)d_in[20];
    const float* W1  = (const float*)d_in[21]; const float* b1  = (const float*)d_in[22];
    const float* W2  = (const float*)d_in[23]; const float* b2  = (const float*)d_in[24];
    float* out = (float*)d_out;

    // workspace layout (floats): q,k,v,skip,h0,h1 [NN*60 each], denom [NN*5]
    float* ws = (float*)d_ws;
    const size_t NHC = (size_t)NN * 60;
    float* qb    = ws;
    float* kb    = qb + NHC;
    float* vb    = kb + NHC;
    float* sb    = vb + NHC;
    float* h0    = sb + NHC;
    float* h1    = h0 + NHC;
    float* denom = h1 + NHC;   // NN*5

    const int qkvs_blocks = (NN + 7) / 8;          // 12500
    const int edge_blocks = NE / 256;              // 6250 exact
    const int epi_blocks  = (NN * 60 + 255) / 256; // 23438
    const int mlp_blocks  = (NN + 255) / 256;      // 391

    // ---- layer 1 ----
    hipMemsetAsync(h0,    0, NHC * sizeof(float), stream);
    hipMemsetAsync(denom, 0, (size_t)NN * NH * sizeof(float), stream);
    qkvs_kernel<FN><<<qkvs_blocks, 256, 0, stream>>>(
        x, Wq1, bq1, Wk1, bk1, Wv1, bv1, Ws1, bs1, qb, kb, vb, sb);
    edge_kernel<<<edge_blocks, 256, 0, stream>>>(ei, ea, We1, qb, kb, vb, denom, h0);
    epilogue_kernel<<<epi_blocks, 256, 0, stream>>>(h0, denom, sb, h0);

    // ---- layer 2 ----
    hipMemsetAsync(h1,    0, NHC * sizeof(float), stream);
    hipMemsetAsync(denom, 0, (size_t)NN * NH * sizeof(float), stream);
    qkvs_kernel<HC><<<qkvs_blocks, 256, 0, stream>>>(
        h0, Wq2, bq2, Wk2, bk2, Wv2, bv2, Ws2, bs2, qb, kb, vb, sb);
    edge_kernel<<<edge_blocks, 256, 0, stream>>>(ei, ea, We2, qb, kb, vb, denom, h1);
    epilogue_kernel<<<epi_blocks, 256, 0, stream>>>(h1, denom, sb, h1);

    // ---- MLP head ----
    mlp_kernel<<<mlp_blocks, 256, 0, stream>>>(h1, W1, b1, W2, b2, out);
}

// Round 3
// 1576.059 us; speedup vs baseline: 7.2833x; 7.2833x over previous
//
#include <hip/hip_runtime.h>
#include <hip/hip_bf16.h>
#include <cstddef>

// Problem constants (from reference)
#define NN 100000
#define NE 1600000
#define NH 5
#define NC 12
#define HC 60     // NH*NC
#define FN 128
#define FE 32
#define HID 16
#define NCLS 2

// ---------------------------------------------------------------------------
// qkvs: computes q,k,v,skip = X @ W? + b?  for 4 weight matrices [DIN,60].
// One block = 8 nodes, 256 threads; threads 0..239 each own (matrix, col).
// ---------------------------------------------------------------------------
template<int DIN>
__global__ __launch_bounds__(256) void qkvs_kernel(
    const float* __restrict__ X,
    const float* __restrict__ Wq, const float* __restrict__ bq,
    const float* __restrict__ Wk, const float* __restrict__ bk,
    const float* __restrict__ Wv, const float* __restrict__ bv,
    const float* __restrict__ Ws, const float* __restrict__ bs,
    float* __restrict__ q, float* __restrict__ k,
    float* __restrict__ v, float* __restrict__ s)
{
    constexpr int NB = 8;
    __shared__ float xs[NB][DIN];
    const int n0 = blockIdx.x * NB;
    for (int i = threadIdx.x; i < NB * DIN; i += 256) {
        const int m = i / DIN, r = i - m * DIN;
        const int node = n0 + m;
        xs[m][r] = (node < NN) ? X[(size_t)node * DIN + r] : 0.f;
    }
    __syncthreads();

    const int j = threadIdx.x;
    if (j >= 240) return;
    const int mat = j / 60, col = j - mat * 60;
    const float* W; const float* b; float* out;
    switch (mat) {
        case 0:  W = Wq; b = bq; out = q; break;
        case 1:  W = Wk; b = bk; out = k; break;
        case 2:  W = Wv; b = bv; out = v; break;
        default: W = Ws; b = bs; out = s; break;
    }
    float acc[NB];
    #pragma unroll
    for (int m = 0; m < NB; ++m) acc[m] = 0.f;
    #pragma unroll 4
    for (int r = 0; r < DIN; ++r) {
        const float w = W[r * 60 + col];
        #pragma unroll
        for (int m = 0; m < NB; ++m) acc[m] = fmaf(xs[m][r], w, acc[m]);
    }
    const float bb = b[col];
    #pragma unroll
    for (int m = 0; m < NB; ++m) {
        const int node = n0 + m;
        if (node < NN) out[(size_t)node * 60 + col] = acc[m] + bb;
    }
}

// ---------------------------------------------------------------------------
// CSR build: histogram of dst -> exclusive scan -> scatter edge ids.
// ---------------------------------------------------------------------------
__global__ __launch_bounds__(256) void hist_kernel(
    const int* __restrict__ ei, int* __restrict__ cnt)
{
    const int e = blockIdx.x * 256 + threadIdx.x;
    if (e < NE) atomicAdd(&cnt[ei[NE + e]], 1);
}

__global__ __launch_bounds__(1024) void scan1_kernel(
    const int* __restrict__ cnt, int* __restrict__ excl, int* __restrict__ bsum)
{
    __shared__ int sh[1024];
    const int i = blockIdx.x * 1024 + threadIdx.x;
    const int v = (i < NN) ? cnt[i] : 0;
    sh[threadIdx.x] = v;
    __syncthreads();
    for (int off = 1; off < 1024; off <<= 1) {
        const int t = (threadIdx.x >= off) ? sh[threadIdx.x - off] : 0;
        __syncthreads();
        sh[threadIdx.x] += t;
        __syncthreads();
    }
    if (i < NN) excl[i] = sh[threadIdx.x] - v;     // block-local exclusive
    if (threadIdx.x == 1023) bsum[blockIdx.x] = sh[1023];
}

__global__ void scan2_kernel(int* __restrict__ bsum, int nb, int* __restrict__ start)
{
    if (threadIdx.x == 0 && blockIdx.x == 0) {
        int acc = 0;
        for (int b = 0; b < nb; ++b) { const int t = bsum[b]; bsum[b] = acc; acc += t; }
        start[NN] = acc;   // == NE
    }
}

__global__ __launch_bounds__(1024) void scan3_kernel(
    int* __restrict__ start, const int* __restrict__ bsum)
{
    const int i = blockIdx.x * 1024 + threadIdx.x;
    if (i < NN) start[i] += bsum[blockIdx.x];
}

__global__ __launch_bounds__(256) void scatter_kernel(
    const int* __restrict__ ei, int* __restrict__ cursor, int* __restrict__ perm)
{
    const int e = blockIdx.x * 256 + threadIdx.x;
    if (e >= NE) return;
    const int d = ei[NE + e];
    const int pos = atomicAdd(&cursor[d], 1);
    perm[pos] = e;
}

// ---------------------------------------------------------------------------
// Aggregation (gather, zero atomics): one wave per dst node, lane = channel hc.
// Per edge e in CSR list of node n:
//   eacc[hc] = sum_r ea[e,r] * We[r,hc]          (We column in 32 registers)
//   p[hc]    = q[n,hc] * (k[src,hc] + eacc[hc])
//   alpha_h  = 12-lane head reduction via ds_bpermute (__shfl) — race-free,
//              exchange happens inside single instructions (no LDS ordering UB)
//   w_h      = exp(alpha_h/sqrt(12) - 20)        (constant shift cancels)
//   acc[hc] += w_h * (v[src,hc] + eacc[hc]);  den += w_h
// Epilogue fused: out = relu(acc/(den+1e-16) + skip).
// ---------------------------------------------------------------------------
__global__ __launch_bounds__(256) void agg_kernel(
    const int* __restrict__ perm, const int* __restrict__ start,
    const int* __restrict__ ei, const float* __restrict__ ea,
    const float* __restrict__ We,
    const float* __restrict__ q, const float* __restrict__ k,
    const float* __restrict__ v, const float* __restrict__ sk,
    float* __restrict__ hout)
{
    const int wv    = threadIdx.x >> 6;
    const int lane  = threadIdx.x & 63;
    const int n     = blockIdx.x * 4 + wv;
    const int hc    = (lane < 60) ? lane : 0;
    const int hd    = hc / NC;          // head 0..4
    const int hbase = hd * NC;          // head's first lane
    const int c     = hc - hbase;       // channel within head, 0..11

    // Precomputed shuffle source lanes for the 12-lane head reduction.
    const int src1 = hbase + ((c + 6) % 12);
    const int src2 = hbase + ((c + 3) % 12);
    const int src3 = hbase + ((c + 1) % 3);
    const int src4 = hbase + ((c + 2) % 3);

    // This lane's We column (fixed for whole kernel): 32 registers.
    float Wcol[FE];
    #pragma unroll
    for (int r = 0; r < FE; ++r) Wcol[r] = We[r * 60 + hc];

    const float qv = q[(size_t)n * 60 + hc];
    const float sv = sk[(size_t)n * 60 + hc];

    const int s0 = __builtin_amdgcn_readfirstlane(start[n]);
    const int s1 = __builtin_amdgcn_readfirstlane(start[n + 1]);

    float acc = 0.f, den = 0.f;
    for (int i = s0; i < s1; ++i) {
        const int e   = __builtin_amdgcn_readfirstlane(perm[i]);
        const int src = __builtin_amdgcn_readfirstlane(ei[e]);
        const float* __restrict__ earow = ea + (size_t)e * FE;
        float eacc = 0.f;
        #pragma unroll
        for (int r = 0; r < FE; ++r) eacc = fmaf(earow[r], Wcol[r], eacc);

        const float kv = k[(size_t)src * 60 + hc];
        const float vv = v[(size_t)src * 60 + hc];
        const float p  = qv * (kv + eacc);

        // 12-lane reduction: fold +6, fold +3 (-> class sums S_{c%3} in every
        // lane), then gather the other two classes. Every lane ends with the
        // full head dot product.
        const float f1 = p  + __shfl(p,  src1);
        const float f2 = f1 + __shfl(f1, src2);
        const float a  = f2 + __shfl(f2, src3) + __shfl(f2, src4);

        // 1/sqrt(12), minus constant shift 20 for exp-range safety
        const float w = __expf(fmaf(a, 0.28867513459481287f, -20.0f));
        acc = fmaf(w, vv + eacc, acc);
        den += w;
    }

    if (lane < 60)
        hout[(size_t)n * 60 + hc] = fmaxf(acc / (den + 1e-16f) + sv, 0.f);
}

// ---------------------------------------------------------------------------
// MLP head: out = relu(h @ W1 + b1) @ W2 + b2     (one thread per node)
// ---------------------------------------------------------------------------
__global__ __launch_bounds__(256) void mlp_kernel(
    const float* __restrict__ h,
    const float* __restrict__ W1, const float* __restrict__ b1,
    const float* __restrict__ W2, const float* __restrict__ b2,
    float* __restrict__ out)
{
    __shared__ float sW1[60 * HID];
    __shared__ float sb1[HID];
    __shared__ float sW2[HID * NCLS];
    __shared__ float sb2[NCLS];
    for (int i = threadIdx.x; i < 60 * HID; i += 256) sW1[i] = W1[i];
    if (threadIdx.x < HID)        sb1[threadIdx.x] = b1[threadIdx.x];
    if (threadIdx.x < HID * NCLS) sW2[threadIdx.x] = W2[threadIdx.x];
    if (threadIdx.x < NCLS)       sb2[threadIdx.x] = b2[threadIdx.x];
    __syncthreads();

    const int n = blockIdx.x * 256 + threadIdx.x;
    if (n >= NN) return;
    const float* __restrict__ hr = h + (size_t)n * 60;
    float hv[60];
    #pragma unroll
    for (int i = 0; i < 15; ++i) {
        const float4 t = ((const float4*)hr)[i];
        hv[4 * i + 0] = t.x; hv[4 * i + 1] = t.y;
        hv[4 * i + 2] = t.z; hv[4 * i + 3] = t.w;
    }
    float o0 = sb2[0], o1 = sb2[1];
    for (int j = 0; j < HID; ++j) {
        float t = sb1[j];
        #pragma unroll
        for (int i = 0; i < 60; ++i) t = fmaf(hv[i], sW1[i * HID + j], t);
        t = fmaxf(t, 0.f);
        o0 = fmaf(t, sW2[2 * j + 0], o0);
        o1 = fmaf(t, sW2[2 * j + 1], o1);
    }
    out[(size_t)n * 2 + 0] = o0;
    out[(size_t)n * 2 + 1] = o1;
}

// ---------------------------------------------------------------------------
extern "C" void kernel_launch(void* const* d_in, const int* in_sizes, int n_in,
                              void* d_out, int out_size, void* d_ws, size_t ws_size,
                              hipStream_t stream)
{
    const float* x   = (const float*)d_in[0];
    const int*   ei  = (const int*)  d_in[1];
    const float* ea  = (const float*)d_in[2];
    const float* Wq1 = (const float*)d_in[3];  const float* bq1 = (const float*)d_in[4];
    const float* Wk1 = (const float*)d_in[5];  const float* bk1 = (const float*)d_in[6];
    const float* Wv1 = (const float*)d_in[7];  const float* bv1 = (const float*)d_in[8];
    const float* We1 = (const float*)d_in[9];
    const float* Ws1 = (const float*)d_in[10]; const float* bs1 = (const float*)d_in[11];
    const float* Wq2 = (const float*)d_in[12]; const float* bq2 = (const float*)d_in[13];
    const float* Wk2 = (const float*)d_in[14]; const float* bk2 = (const float*)d_in[15];
    const float* Wv2 = (const float*)d_in[16]; const float* bv2 = (const float*)d_in[17];
    const float* We2 = (const float*)d_in[18];
    const float* Ws2 = (const float*)d_in[19]; const float* bs2 = (const float*)d_in[20];
    const float* W1  = (const float*)d_in[21]; const float* b1  = (const float*)d_in[22];
    const float* W2  = (const float*)d_in[23]; const float* b2  = (const float*)d_in[24];
    float* out = (float*)d_out;

    // workspace layout: 5 float buffers [NN*60] + CSR int buffers
    float* ws = (float*)d_ws;
    const size_t NHC = (size_t)NN * 60;
    float* qb = ws;
    float* kb = qb + NHC;
    float* vb = kb + NHC;
    float* sb = vb + NHC;
    float* h0 = sb + NHC;                 // layer1 out; overwritten by layer2 out
    int* cnt    = (int*)(h0 + NHC);       // NN
    int* startp = cnt + NN;               // NN+1
    int* cursor = startp + NN + 1;        // NN
    int* bsum   = cursor + NN;            // 128
    int* perm   = bsum + 128;             // NE

    const int qkvs_blocks = (NN + 7) / 8;          // 12500
    const int e256_blocks = NE / 256;              // 6250 exact
    const int scan_blocks = (NN + 1023) / 1024;    // 98
    const int agg_blocks  = NN / 4;                // 25000 exact
    const int mlp_blocks  = (NN + 255) / 256;      // 391

    // ---- CSR build (once, shared by both layers) ----
    hipMemsetAsync(cnt, 0, (size_t)NN * sizeof(int), stream);
    hist_kernel<<<e256_blocks, 256, 0, stream>>>(ei, cnt);
    scan1_kernel<<<scan_blocks, 1024, 0, stream>>>(cnt, startp, bsum);
    scan2_kernel<<<1, 64, 0, stream>>>(bsum, scan_blocks, startp);
    scan3_kernel<<<scan_blocks, 1024, 0, stream>>>(startp, bsum);
    hipMemcpyAsync(cursor, startp, (size_t)NN * sizeof(int),
                   hipMemcpyDeviceToDevice, stream);
    scatter_kernel<<<e256_blocks, 256, 0, stream>>>(ei, cursor, perm);

    // ---- layer 1 ----
    qkvs_kernel<FN><<<qkvs_blocks, 256, 0, stream>>>(
        x, Wq1, bq1, Wk1, bk1, Wv1, bv1, Ws1, bs1, qb, kb, vb, sb);
    agg_kernel<<<agg_blocks, 256, 0, stream>>>(
        perm, startp, ei, ea, We1, qb, kb, vb, sb, h0);

    // ---- layer 2 ----
    qkvs_kernel<HC><<<qkvs_blocks, 256, 0, stream>>>(
        h0, Wq2, bq2, Wk2, bk2, Wv2, bv2, Ws2, bs2, qb, kb, vb, sb);
    agg_kernel<<<agg_blocks, 256, 0, stream>>>(
        perm, startp, ei, ea, We2, qb, kb, vb, sb, h0);   // h0 reuse is safe

    // ---- MLP head ----
    mlp_kernel<<<mlp_blocks, 256, 0, stream>>>(h0, W1, b1, W2, b2, out);
}

// Round 4
// 1408.708 us; speedup vs baseline: 8.1486x; 1.1188x over previous
//
#include <hip/hip_runtime.h>
#include <hip/hip_bf16.h>
#include <cstddef>

// Problem constants (from reference)
#define NN 100000
#define NE 1600000
#define NH 5
#define NC 12
#define HC 60     // NH*NC
#define FN 128
#define FE 32
#define HID 16
#define NCLS 2

// ---------------------------------------------------------------------------
// qkvs: computes q,k,v,skip = X @ W? + b?  for 4 weight matrices [DIN,60].
// One block = 8 nodes, 256 threads; threads 0..239 each own (matrix, col).
// ---------------------------------------------------------------------------
template<int DIN>
__global__ __launch_bounds__(256) void qkvs_kernel(
    const float* __restrict__ X,
    const float* __restrict__ Wq, const float* __restrict__ bq,
    const float* __restrict__ Wk, const float* __restrict__ bk,
    const float* __restrict__ Wv, const float* __restrict__ bv,
    const float* __restrict__ Ws, const float* __restrict__ bs,
    float* __restrict__ q, float* __restrict__ k,
    float* __restrict__ v, float* __restrict__ s)
{
    constexpr int NB = 8;
    __shared__ float xs[NB][DIN];
    const int n0 = blockIdx.x * NB;
    for (int i = threadIdx.x; i < NB * DIN; i += 256) {
        const int m = i / DIN, r = i - m * DIN;
        const int node = n0 + m;
        xs[m][r] = (node < NN) ? X[(size_t)node * DIN + r] : 0.f;
    }
    __syncthreads();

    const int j = threadIdx.x;
    if (j >= 240) return;
    const int mat = j / 60, col = j - mat * 60;
    const float* W; const float* b; float* out;
    switch (mat) {
        case 0:  W = Wq; b = bq; out = q; break;
        case 1:  W = Wk; b = bk; out = k; break;
        case 2:  W = Wv; b = bv; out = v; break;
        default: W = Ws; b = bs; out = s; break;
    }
    float acc[NB];
    #pragma unroll
    for (int m = 0; m < NB; ++m) acc[m] = 0.f;
    #pragma unroll 4
    for (int r = 0; r < DIN; ++r) {
        const float w = W[r * 60 + col];
        #pragma unroll
        for (int m = 0; m < NB; ++m) acc[m] = fmaf(xs[m][r], w, acc[m]);
    }
    const float bb = b[col];
    #pragma unroll
    for (int m = 0; m < NB; ++m) {
        const int node = n0 + m;
        if (node < NN) out[(size_t)node * 60 + col] = acc[m] + bb;
    }
}

// ---------------------------------------------------------------------------
// CSR build: histogram of dst -> exclusive scan -> scatter edge ids (+src ids)
// ---------------------------------------------------------------------------
__global__ __launch_bounds__(256) void hist_kernel(
    const int* __restrict__ ei, int* __restrict__ cnt)
{
    const int e = blockIdx.x * 256 + threadIdx.x;
    if (e < NE) atomicAdd(&cnt[ei[NE + e]], 1);
}

__global__ __launch_bounds__(1024) void scan1_kernel(
    const int* __restrict__ cnt, int* __restrict__ excl, int* __restrict__ bsum)
{
    __shared__ int sh[1024];
    const int i = blockIdx.x * 1024 + threadIdx.x;
    const int v = (i < NN) ? cnt[i] : 0;
    sh[threadIdx.x] = v;
    __syncthreads();
    for (int off = 1; off < 1024; off <<= 1) {
        const int t = (threadIdx.x >= off) ? sh[threadIdx.x - off] : 0;
        __syncthreads();
        sh[threadIdx.x] += t;
        __syncthreads();
    }
    if (i < NN) excl[i] = sh[threadIdx.x] - v;     // block-local exclusive
    if (threadIdx.x == 1023) bsum[blockIdx.x] = sh[1023];
}

__global__ void scan2_kernel(int* __restrict__ bsum, int nb, int* __restrict__ start)
{
    if (threadIdx.x == 0 && blockIdx.x == 0) {
        int acc = 0;
        for (int b = 0; b < nb; ++b) { const int t = bsum[b]; bsum[b] = acc; acc += t; }
        start[NN] = acc;   // == NE
    }
}

__global__ __launch_bounds__(1024) void scan3_kernel(
    int* __restrict__ start, const int* __restrict__ bsum)
{
    const int i = blockIdx.x * 1024 + threadIdx.x;
    if (i < NN) start[i] += bsum[blockIdx.x];
}

__global__ __launch_bounds__(256) void scatter_kernel(
    const int* __restrict__ ei, int* __restrict__ cursor,
    int* __restrict__ perm, int* __restrict__ srcs)
{
    const int e = blockIdx.x * 256 + threadIdx.x;
    if (e >= NE) return;
    const int d = ei[NE + e];
    const int pos = atomicAdd(&cursor[d], 1);
    perm[pos] = e;
    srcs[pos] = ei[e];   // materialize src: kills one dependent load in agg
}

// ---------------------------------------------------------------------------
// Aggregation (gather, zero atomics): one wave per dst node, lane = channel hc.
// Edge indices for up to 64 edges are loaded coalesced into registers
// (lane j holds pair j), then broadcast per edge via __shfl — no per-edge
// index loads. ea/k/v for edge t+1 are prefetched while edge t computes.
// ---------------------------------------------------------------------------
__global__ __launch_bounds__(256) void agg_kernel(
    const int* __restrict__ perm, const int* __restrict__ srcs,
    const int* __restrict__ start,
    const float* __restrict__ ea, const float* __restrict__ We,
    const float* __restrict__ q, const float* __restrict__ k,
    const float* __restrict__ v, const float* __restrict__ sk,
    float* __restrict__ hout)
{
    const int wv    = threadIdx.x >> 6;
    const int lane  = threadIdx.x & 63;
    const int n     = blockIdx.x * 4 + wv;
    const int hc    = (lane < 60) ? lane : 0;
    const int hd    = hc / NC;          // head 0..4
    const int hbase = hd * NC;          // head's first lane
    const int c     = hc - hbase;       // channel within head, 0..11

    // Shuffle source lanes for the 12-lane head reduction.
    const int r1 = hbase + ((c + 6) % 12);
    const int r2 = hbase + ((c + 3) % 12);
    const int r3 = hbase + ((c + 1) % 3);
    const int r4 = hbase + ((c + 2) % 3);

    // This lane's We column (fixed for whole kernel): 32 registers.
    float Wcol[FE];
    #pragma unroll
    for (int r = 0; r < FE; ++r) Wcol[r] = We[r * 60 + hc];

    const float qv = q[(size_t)n * 60 + hc];
    const float sv = sk[(size_t)n * 60 + hc];

    const int s0 = __builtin_amdgcn_readfirstlane(start[n]);
    const int s1 = __builtin_amdgcn_readfirstlane(start[n + 1]);

    float acc = 0.f, den = 0.f;

    for (int c0 = s0; c0 < s1; c0 += 64) {
        const int cnt = min(64, s1 - c0);

        // One coalesced load: lane j holds (edge, src) for CSR slot c0+j.
        int myE = 0, myS = 0;
        if (c0 + lane < s1) { myE = perm[c0 + lane]; myS = srcs[c0 + lane]; }

        // Pipelined state (A = current, B = next)
        float eaA[FE], eaB[FE], kvA, vvA, kvB, vvB;

        {   // prologue: load edge 0
            const int e = __builtin_amdgcn_readfirstlane(__shfl(myE, 0));
            const int s = __builtin_amdgcn_readfirstlane(__shfl(myS, 0));
            const float* __restrict__ er = ea + (size_t)e * FE;
            #pragma unroll
            for (int r = 0; r < FE; ++r) eaA[r] = er[r];
            kvA = k[(size_t)s * 60 + hc];
            vvA = v[(size_t)s * 60 + hc];
        }

        for (int t = 0; t < cnt; t += 2) {
            if (t + 1 < cnt) {  // prefetch edge t+1 while computing t
                const int e = __builtin_amdgcn_readfirstlane(__shfl(myE, t + 1));
                const int s = __builtin_amdgcn_readfirstlane(__shfl(myS, t + 1));
                const float* __restrict__ er = ea + (size_t)e * FE;
                #pragma unroll
                for (int r = 0; r < FE; ++r) eaB[r] = er[r];
                kvB = k[(size_t)s * 60 + hc];
                vvB = v[(size_t)s * 60 + hc];
            }
            {   // compute edge t
                float e0 = 0.f, e1 = 0.f;
                #pragma unroll
                for (int r = 0; r < FE; r += 2) {
                    e0 = fmaf(eaA[r],     Wcol[r],     e0);
                    e1 = fmaf(eaA[r + 1], Wcol[r + 1], e1);
                }
                const float eacc = e0 + e1;
                const float p  = qv * (kvA + eacc);
                const float f1 = p  + __shfl(p,  r1);
                const float f2 = f1 + __shfl(f1, r2);
                const float a  = f2 + __shfl(f2, r3) + __shfl(f2, r4);
                const float w  = __expf(fmaf(a, 0.28867513459481287f, -20.0f));
                acc = fmaf(w, vvA + eacc, acc);
                den += w;
            }
            if (t + 2 < cnt) {  // prefetch edge t+2 while computing t+1
                const int e = __builtin_amdgcn_readfirstlane(__shfl(myE, t + 2));
                const int s = __builtin_amdgcn_readfirstlane(__shfl(myS, t + 2));
                const float* __restrict__ er = ea + (size_t)e * FE;
                #pragma unroll
                for (int r = 0; r < FE; ++r) eaA[r] = er[r];
                kvA = k[(size_t)s * 60 + hc];
                vvA = v[(size_t)s * 60 + hc];
            }
            if (t + 1 < cnt) {  // compute edge t+1
                float e0 = 0.f, e1 = 0.f;
                #pragma unroll
                for (int r = 0; r < FE; r += 2) {
                    e0 = fmaf(eaB[r],     Wcol[r],     e0);
                    e1 = fmaf(eaB[r + 1], Wcol[r + 1], e1);
                }
                const float eacc = e0 + e1;
                const float p  = qv * (kvB + eacc);
                const float f1 = p  + __shfl(p,  r1);
                const float f2 = f1 + __shfl(f1, r2);
                const float a  = f2 + __shfl(f2, r3) + __shfl(f2, r4);
                const float w  = __expf(fmaf(a, 0.28867513459481287f, -20.0f));
                acc = fmaf(w, vvB + eacc, acc);
                den += w;
            }
        }
    }

    if (lane < 60)
        hout[(size_t)n * 60 + hc] = fmaxf(acc / (den + 1e-16f) + sv, 0.f);
}

// ---------------------------------------------------------------------------
// MLP head: out = relu(h @ W1 + b1) @ W2 + b2     (one thread per node)
// ---------------------------------------------------------------------------
__global__ __launch_bounds__(256) void mlp_kernel(
    const float* __restrict__ h,
    const float* __restrict__ W1, const float* __restrict__ b1,
    const float* __restrict__ W2, const float* __restrict__ b2,
    float* __restrict__ out)
{
    __shared__ float sW1[60 * HID];
    __shared__ float sb1[HID];
    __shared__ float sW2[HID * NCLS];
    __shared__ float sb2[NCLS];
    for (int i = threadIdx.x; i < 60 * HID; i += 256) sW1[i] = W1[i];
    if (threadIdx.x < HID)        sb1[threadIdx.x] = b1[threadIdx.x];
    if (threadIdx.x < HID * NCLS) sW2[threadIdx.x] = W2[threadIdx.x];
    if (threadIdx.x < NCLS)       sb2[threadIdx.x] = b2[threadIdx.x];
    __syncthreads();

    const int n = blockIdx.x * 256 + threadIdx.x;
    if (n >= NN) return;
    const float* __restrict__ hr = h + (size_t)n * 60;
    float hv[60];
    #pragma unroll
    for (int i = 0; i < 15; ++i) {
        const float4 t = ((const float4*)hr)[i];
        hv[4 * i + 0] = t.x; hv[4 * i + 1] = t.y;
        hv[4 * i + 2] = t.z; hv[4 * i + 3] = t.w;
    }
    float o0 = sb2[0], o1 = sb2[1];
    for (int j = 0; j < HID; ++j) {
        float t = sb1[j];
        #pragma unroll
        for (int i = 0; i < 60; ++i) t = fmaf(hv[i], sW1[i * HID + j], t);
        t = fmaxf(t, 0.f);
        o0 = fmaf(t, sW2[2 * j + 0], o0);
        o1 = fmaf(t, sW2[2 * j + 1], o1);
    }
    out[(size_t)n * 2 + 0] = o0;
    out[(size_t)n * 2 + 1] = o1;
}

// ---------------------------------------------------------------------------
extern "C" void kernel_launch(void* const* d_in, const int* in_sizes, int n_in,
                              void* d_out, int out_size, void* d_ws, size_t ws_size,
                              hipStream_t stream)
{
    const float* x   = (const float*)d_in[0];
    const int*   ei  = (const int*)  d_in[1];
    const float* ea  = (const float*)d_in[2];
    const float* Wq1 = (const float*)d_in[3];  const float* bq1 = (const float*)d_in[4];
    const float* Wk1 = (const float*)d_in[5];  const float* bk1 = (const float*)d_in[6];
    const float* Wv1 = (const float*)d_in[7];  const float* bv1 = (const float*)d_in[8];
    const float* We1 = (const float*)d_in[9];
    const float* Ws1 = (const float*)d_in[10]; const float* bs1 = (const float*)d_in[11];
    const float* Wq2 = (const float*)d_in[12]; const float* bq2 = (const float*)d_in[13];
    const float* Wk2 = (const float*)d_in[14]; const float* bk2 = (const float*)d_in[15];
    const float* Wv2 = (const float*)d_in[16]; const float* bv2 = (const float*)d_in[17];
    const float* We2 = (const float*)d_in[18];
    const float* Ws2 = (const float*)d_in[19]; const float* bs2 = (const float*)d_in[20];
    const float* W1  = (const float*)d_in[21]; const float* b1  = (const float*)d_in[22];
    const float* W2  = (const float*)d_in[23]; const float* b2  = (const float*)d_in[24];
    float* out = (float*)d_out;

    // workspace layout: 5 float buffers [NN*60] + CSR int buffers
    float* ws = (float*)d_ws;
    const size_t NHC = (size_t)NN * 60;
    float* qb = ws;
    float* kb = qb + NHC;
    float* vb = kb + NHC;
    float* sb = vb + NHC;
    float* h0 = sb + NHC;                 // layer1 out; overwritten by layer2 out
    int* cnt    = (int*)(h0 + NHC);       // NN
    int* startp = cnt + NN;               // NN+1
    int* cursor = startp + NN + 1;        // NN
    int* bsum   = cursor + NN;            // 128
    int* perm   = bsum + 128;             // NE
    int* srcs   = perm + NE;              // NE

    const int qkvs_blocks = (NN + 7) / 8;          // 12500
    const int e256_blocks = NE / 256;              // 6250 exact
    const int scan_blocks = (NN + 1023) / 1024;    // 98
    const int agg_blocks  = NN / 4;                // 25000 exact
    const int mlp_blocks  = (NN + 255) / 256;      // 391

    // ---- CSR build (once, shared by both layers) ----
    hipMemsetAsync(cnt, 0, (size_t)NN * sizeof(int), stream);
    hist_kernel<<<e256_blocks, 256, 0, stream>>>(ei, cnt);
    scan1_kernel<<<scan_blocks, 1024, 0, stream>>>(cnt, startp, bsum);
    scan2_kernel<<<1, 64, 0, stream>>>(bsum, scan_blocks, startp);
    scan3_kernel<<<scan_blocks, 1024, 0, stream>>>(startp, bsum);
    hipMemcpyAsync(cursor, startp, (size_t)NN * sizeof(int),
                   hipMemcpyDeviceToDevice, stream);
    scatter_kernel<<<e256_blocks, 256, 0, stream>>>(ei, cursor, perm, srcs);

    // ---- layer 1 ----
    qkvs_kernel<FN><<<qkvs_blocks, 256, 0, stream>>>(
        x, Wq1, bq1, Wk1, bk1, Wv1, bv1, Ws1, bs1, qb, kb, vb, sb);
    agg_kernel<<<agg_blocks, 256, 0, stream>>>(
        perm, srcs, startp, ea, We1, qb, kb, vb, sb, h0);

    // ---- layer 2 ----
    qkvs_kernel<HC><<<qkvs_blocks, 256, 0, stream>>>(
        h0, Wq2, bq2, Wk2, bk2, Wv2, bv2, Ws2, bs2, qb, kb, vb, sb);
    agg_kernel<<<agg_blocks, 256, 0, stream>>>(
        perm, srcs, startp, ea, We2, qb, kb, vb, sb, h0);   // h0 reuse is safe

    // ---- MLP head ----
    mlp_kernel<<<mlp_blocks, 256, 0, stream>>>(h0, W1, b1, W2, b2, out);
}